// Round 1
// baseline (384.147 us; speedup 1.0000x reference)
//
#include <hip/hip_runtime.h>
#include <hip/hip_bf16.h>
#include <stdint.h>

// Problem constants
static constexpr int kB = 4;
static constexpr int kT = 2048;
static constexpr int kE = 1024;
static constexpr int kH = 16;
static constexpr int kS = 64;          // head dim
static constexpr int kRows = kB * kT;  // 8192

typedef __attribute__((ext_vector_type(4))) float  f32x4;
typedef __attribute__((ext_vector_type(4))) float  float4v;
typedef __attribute__((ext_vector_type(8))) __bf16 bf16x8;
typedef __attribute__((ext_vector_type(8))) short  short8v;
typedef __attribute__((ext_vector_type(4))) short  short4v;

__device__ __forceinline__ short f2bf(float f) {
  union { float f; unsigned u; } c; c.f = f;
  unsigned r = (c.u + 0x7FFFu + ((c.u >> 16) & 1u)) >> 16;
  return (short)(r & 0xFFFFu);
}

// ---------------- convert f32 -> bf16 (vectorized) ----------------
__global__ void cvt_bf16(const float* __restrict__ in, short* __restrict__ out) {
  size_t i = (size_t)(blockIdx.x * blockDim.x + threadIdx.x) * 4;
  float4v x = *(const float4v*)(in + i);
  short4v o;
  o[0] = f2bf(x[0]); o[1] = f2bf(x[1]); o[2] = f2bf(x[2]); o[3] = f2bf(x[3]);
  *(short4v*)(out + i) = o;
}

// ---------------- transpose + convert: W[k][n] f32 -> WT[n][k] bf16 ----------------
__global__ void transpose_cvt(const float* __restrict__ W, short* __restrict__ WT) {
  __shared__ float tile[32][33];
  const int tx = threadIdx.x & 31, ty = threadIdx.x >> 5;  // 32 x 8
  const int c = blockIdx.x * 32, r = blockIdx.y * 32;
  #pragma unroll
  for (int i = ty; i < 32; i += 8)
    tile[i][tx] = W[(size_t)(r + i) * kE + c + tx];
  __syncthreads();
  #pragma unroll
  for (int i = ty; i < 32; i += 8)
    WT[(size_t)(c + i) * kE + r + tx] = f2bf(tile[tx][i]);
}

// ---------------- bf16 GEMM: C[M,N] = scale * (A[M,K] @ BT[N,K]^T) (+bias) ----------------
template<int OUT_BF16>
__global__ __launch_bounds__(256)
void gemm_bt(const short* __restrict__ A, const short* __restrict__ BT,
             void* __restrict__ Cout, const float* __restrict__ bias,
             float scale, int M, int N, int K) {
  constexpr int LDT = 40;  // 32 + 8 pad (keeps 16B alignment, breaks bank conflicts)
  __shared__ short As[128 * LDT];
  __shared__ short Bs[128 * LDT];
  const int tid  = threadIdx.x;
  const int wid  = tid >> 6, lane = tid & 63;
  const int g    = lane >> 4, lr = lane & 15;
  const int n0   = blockIdx.x * 128, m0 = blockIdx.y * 128;
  const int wr   = wid >> 1, wc = wid & 1;   // 2x2 waves, 64x64 each

  f32x4 acc[4][4];
  #pragma unroll
  for (int m = 0; m < 4; ++m)
    #pragma unroll
    for (int n = 0; n < 4; ++n)
      #pragma unroll
      for (int r = 0; r < 4; ++r) acc[m][n][r] = 0.f;

  const int c0 = (tid & 3) * 8;   // k-chunk within 32
  for (int kt = 0; kt < K; kt += 32) {
    #pragma unroll
    for (int p = 0; p < 2; ++p) {
      int r = p * 64 + (tid >> 2);  // tile row 0..127
      short8v va = *(const short8v*)(A  + (size_t)(m0 + r) * K + kt + c0);
      short8v vb = *(const short8v*)(BT + (size_t)(n0 + r) * K + kt + c0);
      *(short8v*)(As + r * LDT + c0) = va;
      *(short8v*)(Bs + r * LDT + c0) = vb;
    }
    __syncthreads();

    bf16x8 af[4], bf[4];
    #pragma unroll
    for (int m = 0; m < 4; ++m)
      af[m] = *(const bf16x8*)(As + (wr * 64 + m * 16 + lr) * LDT + 8 * g);
    #pragma unroll
    for (int n = 0; n < 4; ++n)
      bf[n] = *(const bf16x8*)(Bs + (wc * 64 + n * 16 + lr) * LDT + 8 * g);

    #pragma unroll
    for (int m = 0; m < 4; ++m)
      #pragma unroll
      for (int n = 0; n < 4; ++n)
        acc[m][n] = __builtin_amdgcn_mfma_f32_16x16x32_bf16(af[m], bf[n], acc[m][n], 0, 0, 0);
    __syncthreads();
  }

  const int crow = m0 + wr * 64, ccol = n0 + wc * 64;
  if (OUT_BF16) {
    short* C = (short*)Cout;
    #pragma unroll
    for (int m = 0; m < 4; ++m)
      #pragma unroll
      for (int n = 0; n < 4; ++n)
        #pragma unroll
        for (int r = 0; r < 4; ++r)
          C[(size_t)(crow + m * 16 + 4 * g + r) * N + ccol + n * 16 + lr] =
              f2bf(acc[m][n][r] * scale);
  } else {
    float* C = (float*)Cout;
    float bv[4];
    #pragma unroll
    for (int n = 0; n < 4; ++n) bv[n] = bias ? bias[ccol + n * 16 + lr] : 0.f;
    #pragma unroll
    for (int m = 0; m < 4; ++m)
      #pragma unroll
      for (int n = 0; n < 4; ++n)
        #pragma unroll
        for (int r = 0; r < 4; ++r)
          C[(size_t)(crow + m * 16 + 4 * g + r) * N + ccol + n * 16 + lr] =
              acc[m][n][r] * scale + bv[n];
  }
}

// ---------------- flash attention; V == K (faithful to reference bug) ----------------
// Q pre-scaled by E^-0.5. Layout: Qb/Kb/AO are [8192][1024] bf16, head h at cols h*64..
__global__ __launch_bounds__(256)
void attn_kernel(const short* __restrict__ Qb, const short* __restrict__ Kb,
                 short* __restrict__ AO) {
  constexpr int LD = 72;              // padded row stride (16B-aligned, conflict-light)
  __shared__ short Kt[64 * LD];       // [kv][s]   - B-frags for QK^T
  __shared__ short Vt[64 * LD];       // [s][kv]   - B-frags for PV (transposed K)
  __shared__ short Pt[64 * LD];       // [q][kv]   - A-frags for PV

  const int tid  = threadIdx.x;
  const int wid  = tid >> 6, lane = tid & 63;
  const int g    = lane >> 4, lr = lane & 15;
  const int bh   = blockIdx.y, b = bh >> 4, h = bh & 15;
  const int q0   = blockIdx.x * 64;
  const int strip = wid * 16;
  const size_t base = (size_t)b * kT * kE + (size_t)h * kS;

  bf16x8 qf[2];
  {
    const short* qrow = Qb + base + (size_t)(q0 + strip + lr) * kE;
    qf[0] = *(const bf16x8*)(qrow + 8 * g);
    qf[1] = *(const bf16x8*)(qrow + 32 + 8 * g);
  }

  f32x4 oacc[4];
  #pragma unroll
  for (int n = 0; n < 4; ++n)
    #pragma unroll
    for (int r = 0; r < 4; ++r) oacc[n][r] = 0.f;
  float mrow[4] = {-1e30f, -1e30f, -1e30f, -1e30f};
  float lrow[4] = {0.f, 0.f, 0.f, 0.f};

  for (int kv0 = 0; kv0 < kT; kv0 += 64) {
    const short* kb = Kb + base + (size_t)kv0 * kE;
    #pragma unroll
    for (int p = 0; p < 2; ++p) {
      {  // Kt [kv][s]: row-coalesced
        int r = p * 32 + (tid >> 3), c = 8 * (tid & 7);
        short8v v = *(const short8v*)(kb + (size_t)r * kE + c);
        *(short8v*)(Kt + r * LD + c) = v;
      }
      {  // Vt [s][kv]: transposed write (conflict-free: r spans 64 rows across lanes)
        int r = tid & 63, c = 8 * (p * 4 + (tid >> 6));
        short8v v = *(const short8v*)(kb + (size_t)r * kE + c);
        #pragma unroll
        for (int j = 0; j < 8; ++j) Vt[(c + j) * LD + r] = v[j];
      }
    }
    __syncthreads();

    // S = Q K^T   (16 q-rows per wave x 64 kv)
    f32x4 sacc[4];
    #pragma unroll
    for (int n = 0; n < 4; ++n)
      #pragma unroll
      for (int r = 0; r < 4; ++r) sacc[n][r] = 0.f;
    #pragma unroll
    for (int kk = 0; kk < 2; ++kk)
      #pragma unroll
      for (int n = 0; n < 4; ++n) {
        bf16x8 bfr = *(const bf16x8*)(Kt + (lr + 16 * n) * LD + 32 * kk + 8 * g);
        sacc[n] = __builtin_amdgcn_mfma_f32_16x16x32_bf16(qf[kk], bfr, sacc[n], 0, 0, 0);
      }

    // online softmax (row r of lane = q-local 4g+r; 16-lane group reduce)
    float al[4];
    #pragma unroll
    for (int r = 0; r < 4; ++r) {
      float t = fmaxf(fmaxf(sacc[0][r], sacc[1][r]), fmaxf(sacc[2][r], sacc[3][r]));
      t = fmaxf(t, __shfl_xor(t, 1));
      t = fmaxf(t, __shfl_xor(t, 2));
      t = fmaxf(t, __shfl_xor(t, 4));
      t = fmaxf(t, __shfl_xor(t, 8));
      float mn = fmaxf(mrow[r], t);
      al[r] = exp2f((mrow[r] - mn) * 1.44269504f);
      mrow[r] = mn;
    }
    float rs[4] = {0.f, 0.f, 0.f, 0.f};
    #pragma unroll
    for (int n = 0; n < 4; ++n)
      #pragma unroll
      for (int r = 0; r < 4; ++r) {
        float pv = exp2f((sacc[n][r] - mrow[r]) * 1.44269504f);
        rs[r] += pv;
        Pt[(strip + 4 * g + r) * LD + 16 * n + lr] = f2bf(pv);
      }
    #pragma unroll
    for (int r = 0; r < 4; ++r) {
      float s = rs[r];
      s += __shfl_xor(s, 1); s += __shfl_xor(s, 2);
      s += __shfl_xor(s, 4); s += __shfl_xor(s, 8);
      lrow[r] = lrow[r] * al[r] + s;
      #pragma unroll
      for (int n = 0; n < 4; ++n) oacc[n][r] *= al[r];
    }
    __syncthreads();  // P visible (and K-tile QK^T reads done)

    // O += P V
    #pragma unroll
    for (int kk = 0; kk < 2; ++kk) {
      bf16x8 pa = *(const bf16x8*)(Pt + (strip + lr) * LD + 32 * kk + 8 * g);
      #pragma unroll
      for (int n = 0; n < 4; ++n) {
        bf16x8 vfr = *(const bf16x8*)(Vt + (lr + 16 * n) * LD + 32 * kk + 8 * g);
        oacc[n] = __builtin_amdgcn_mfma_f32_16x16x32_bf16(pa, vfr, oacc[n], 0, 0, 0);
      }
    }
    __syncthreads();  // PV reads done before next staging
  }

  #pragma unroll
  for (int n = 0; n < 4; ++n)
    #pragma unroll
    for (int r = 0; r < 4; ++r) {
      int qr = q0 + strip + 4 * g + r;
      AO[base + (size_t)qr * kE + 16 * n + lr] = f2bf(oacc[n][r] / lrow[r]);
    }
}

// ---------------- launch ----------------
extern "C" void kernel_launch(void* const* d_in, const int* in_sizes, int n_in,
                              void* d_out, int out_size, void* d_ws, size_t ws_size,
                              hipStream_t stream) {
  const float* x  = (const float*)d_in[0];
  const float* Wk = (const float*)d_in[1];
  const float* Wq = (const float*)d_in[2];
  const float* Wo = (const float*)d_in[3];
  const float* bo = (const float*)d_in[4];
  float* out = (float*)d_out;

  const size_t nXE = (size_t)kRows * kE;  // 8388608
  const size_t nW  = (size_t)kE * kE;     // 1048576

  short* Xb  = (short*)d_ws;
  short* Kb  = Xb  + nXE;
  short* Qb  = Kb  + nXE;
  short* WkT = Qb  + nXE;
  short* WqT = WkT + nW;
  short* WoT = WqT + nW;
  short* AO  = Xb;  // reuse: x no longer needed after projections

  // x -> bf16
  cvt_bf16<<<dim3(nXE / (4 * 256)), 256, 0, stream>>>(x, Xb);
  // W^T -> bf16
  transpose_cvt<<<dim3(32, 32), 256, 0, stream>>>(Wk, WkT);
  transpose_cvt<<<dim3(32, 32), 256, 0, stream>>>(Wq, WqT);
  transpose_cvt<<<dim3(32, 32), 256, 0, stream>>>(Wo, WoT);

  // K (=V) and Q projections; fold score scale E^-0.5 = 1/32 into Q
  gemm_bt<1><<<dim3(kE / 128, kRows / 128), 256, 0, stream>>>(
      Xb, WkT, (void*)Kb, nullptr, 1.0f, kRows, kE, kE);
  gemm_bt<1><<<dim3(kE / 128, kRows / 128), 256, 0, stream>>>(
      Xb, WqT, (void*)Qb, nullptr, 0.03125f, kRows, kE, kE);

  // attention (writes AO over Xb)
  attn_kernel<<<dim3(kT / 64, kB * kH), 256, 0, stream>>>(Qb, Kb, AO);

  // output projection + bias
  gemm_bt<0><<<dim3(kE / 128, kRows / 128), 256, 0, stream>>>(
      AO, WoT, (void*)out, bo, 1.0f, kRows, kE, kE);
}

// Round 2
// 317.038 us; speedup vs baseline: 1.2117x; 1.2117x over previous
//
#include <hip/hip_runtime.h>
#include <hip/hip_bf16.h>
#include <stdint.h>

// Problem constants
static constexpr int kB = 4;
static constexpr int kT = 2048;
static constexpr int kE = 1024;
static constexpr int kH = 16;
static constexpr int kS = 64;          // head dim
static constexpr int kRows = kB * kT;  // 8192

typedef __attribute__((ext_vector_type(4))) float  f32x4;
typedef __attribute__((ext_vector_type(4))) float  float4v;
typedef __attribute__((ext_vector_type(8))) __bf16 bf16x8;
typedef __attribute__((ext_vector_type(8))) short  short8v;
typedef __attribute__((ext_vector_type(4))) short  short4v;

typedef const __attribute__((address_space(1))) void gvoid_t;
typedef __attribute__((address_space(3))) void lvoid_t;

__device__ __forceinline__ short f2bf(float f) {
  union { float f; unsigned u; } c; c.f = f;
  unsigned r = (c.u + 0x7FFFu + ((c.u >> 16) & 1u)) >> 16;
  return (short)(r & 0xFFFFu);
}

// native f32->bf16 (compiler emits v_cvt; m240: don't hand-write)
__device__ __forceinline__ short bfc(float f) {
  union { __bf16 b; short s; } u; u.b = (__bf16)f; return u.s;
}

#if __has_builtin(__builtin_amdgcn_exp2f)
__device__ __forceinline__ float fexp2(float x) { return __builtin_amdgcn_exp2f(x); }
#else
__device__ __forceinline__ float fexp2(float x) { return exp2f(x); }
#endif

// ---------------- convert f32 -> bf16 (vectorized) ----------------
__global__ void cvt_bf16(const float* __restrict__ in, short* __restrict__ out) {
  size_t i = (size_t)(blockIdx.x * blockDim.x + threadIdx.x) * 4;
  float4v x = *(const float4v*)(in + i);
  short4v o;
  o[0] = f2bf(x[0]); o[1] = f2bf(x[1]); o[2] = f2bf(x[2]); o[3] = f2bf(x[3]);
  *(short4v*)(out + i) = o;
}

// ---------------- transpose + convert: W[k][n] f32 -> WT[n][k] bf16 ----------------
__global__ void transpose_cvt(const float* __restrict__ W, short* __restrict__ WT) {
  __shared__ float tile[32][33];
  const int tx = threadIdx.x & 31, ty = threadIdx.x >> 5;  // 32 x 8
  const int c = blockIdx.x * 32, r = blockIdx.y * 32;
  #pragma unroll
  for (int i = ty; i < 32; i += 8)
    tile[i][tx] = W[(size_t)(r + i) * kE + c + tx];
  __syncthreads();
  #pragma unroll
  for (int i = ty; i < 32; i += 8)
    WT[(size_t)(c + i) * kE + r + tx] = f2bf(tile[tx][i]);
}

// ---------------- bf16 GEMM: C[M,N] = scale * (A[M,K] @ BT[N,K]^T) (+bias) ----------------
template<int OUT_BF16>
__global__ __launch_bounds__(256)
void gemm_bt(const short* __restrict__ A, const short* __restrict__ BT,
             void* __restrict__ Cout, const float* __restrict__ bias,
             float scale, int M, int N, int K) {
  constexpr int LDT = 40;  // 32 + 8 pad (keeps 16B alignment, breaks bank conflicts)
  __shared__ short As[128 * LDT];
  __shared__ short Bs[128 * LDT];
  const int tid  = threadIdx.x;
  const int wid  = tid >> 6, lane = tid & 63;
  const int g    = lane >> 4, lr = lane & 15;
  const int n0   = blockIdx.x * 128, m0 = blockIdx.y * 128;
  const int wr   = wid >> 1, wc = wid & 1;   // 2x2 waves, 64x64 each

  f32x4 acc[4][4];
  #pragma unroll
  for (int m = 0; m < 4; ++m)
    #pragma unroll
    for (int n = 0; n < 4; ++n)
      #pragma unroll
      for (int r = 0; r < 4; ++r) acc[m][n][r] = 0.f;

  const int c0 = (tid & 3) * 8;   // k-chunk within 32
  for (int kt = 0; kt < K; kt += 32) {
    #pragma unroll
    for (int p = 0; p < 2; ++p) {
      int r = p * 64 + (tid >> 2);  // tile row 0..127
      short8v va = *(const short8v*)(A  + (size_t)(m0 + r) * K + kt + c0);
      short8v vb = *(const short8v*)(BT + (size_t)(n0 + r) * K + kt + c0);
      *(short8v*)(As + r * LDT + c0) = va;
      *(short8v*)(Bs + r * LDT + c0) = vb;
    }
    __syncthreads();

    bf16x8 af[4], bf[4];
    #pragma unroll
    for (int m = 0; m < 4; ++m)
      af[m] = *(const bf16x8*)(As + (wr * 64 + m * 16 + lr) * LDT + 8 * g);
    #pragma unroll
    for (int n = 0; n < 4; ++n)
      bf[n] = *(const bf16x8*)(Bs + (wc * 64 + n * 16 + lr) * LDT + 8 * g);

    #pragma unroll
    for (int m = 0; m < 4; ++m)
      #pragma unroll
      for (int n = 0; n < 4; ++n)
        acc[m][n] = __builtin_amdgcn_mfma_f32_16x16x32_bf16(af[m], bf[n], acc[m][n], 0, 0, 0);
    __syncthreads();
  }

  const int crow = m0 + wr * 64, ccol = n0 + wc * 64;
  if (OUT_BF16) {
    short* C = (short*)Cout;
    #pragma unroll
    for (int m = 0; m < 4; ++m)
      #pragma unroll
      for (int n = 0; n < 4; ++n)
        #pragma unroll
        for (int r = 0; r < 4; ++r)
          C[(size_t)(crow + m * 16 + 4 * g + r) * N + ccol + n * 16 + lr] =
              bfc(acc[m][n][r] * scale);
  } else {
    float* C = (float*)Cout;
    float bv[4];
    #pragma unroll
    for (int n = 0; n < 4; ++n) bv[n] = bias ? bias[ccol + n * 16 + lr] : 0.f;
    #pragma unroll
    for (int m = 0; m < 4; ++m)
      #pragma unroll
      for (int n = 0; n < 4; ++n)
        #pragma unroll
        for (int r = 0; r < 4; ++r)
          C[(size_t)(crow + m * 16 + 4 * g + r) * N + ccol + n * 16 + lr] =
              acc[m][n][r] * scale + bv[n];
  }
}

// ---------------- flash attention; V == K (faithful to reference bug) ----------------
// QBLK=128 (4 waves x 32 q-rows), KVBLK=64.
// Kt [kv][s]: linear 128B rows, XOR-chunk-swizzled content via pre-swizzled
//             global source + global_load_lds (16B).
// Vt [s][kv]: transposed K, swizzled writes/reads.
// Pt [q][kv]: wave-private P tiles, swizzled.
// Swizzle: 16B chunk index c within a 128B row -> c ^ (row & 7).
__global__ __launch_bounds__(256)
void attn_kernel(const short* __restrict__ Qb, const short* __restrict__ Kb,
                 short* __restrict__ AO) {
  __shared__ short Kt[64 * 64];
  __shared__ short Vt[64 * 64];
  __shared__ short Pt[128 * 64];

  const int tid = threadIdx.x;
  const int w = tid >> 6, lane = tid & 63;
  const int g = lane >> 4, lr = lane & 15;
  const int bh = blockIdx.y, b = bh >> 4, h = bh & 15;
  const int q0 = blockIdx.x * 128;
  const size_t base = (size_t)b * kT * kE + (size_t)h * kS;

  // Q fragments: wave w owns q rows q0 + w*32 + {0..31}
  bf16x8 qf[2][2];
  #pragma unroll
  for (int m = 0; m < 2; ++m)
    #pragma unroll
    for (int kk = 0; kk < 2; ++kk)
      qf[m][kk] = *(const bf16x8*)(Qb + base +
          (size_t)(q0 + w * 32 + m * 16 + lr) * kE + 32 * kk + 8 * g);

  f32x4 oacc[2][4];
  f32x4 lacc[2];
  #pragma unroll
  for (int m = 0; m < 2; ++m) {
    #pragma unroll
    for (int n = 0; n < 4; ++n)
      #pragma unroll
      for (int r = 0; r < 4; ++r) oacc[m][n][r] = 0.f;
    #pragma unroll
    for (int r = 0; r < 4; ++r) lacc[m][r] = 0.f;
  }
  float mrow[2][4];
  #pragma unroll
  for (int m = 0; m < 2; ++m)
    #pragma unroll
    for (int r = 0; r < 4; ++r) mrow[m][r] = -1e30f;

  // ones B-fragment for row-sum-via-MFMA
  short8v ones_i;
  #pragma unroll
  for (int j = 0; j < 8; ++j) ones_i[j] = 0x3F80;
  const bf16x8 onef = *(const bf16x8*)&ones_i;

  const int swz = lr & 7;  // row&7 for all per-lane frag rows (16n+lr etc.)

  for (int kv0 = 0; kv0 < kT; kv0 += 64) {
    const short* kb = Kb + base + (size_t)kv0 * kE;

    // ---- stage Kt: direct global->LDS, source chunk pre-swizzled ----
    #pragma unroll
    for (int i = 0; i < 2; ++i) {
      const int slot = w * 2 + i;              // 8 x 1024B slots
      const int row  = slot * 8 + (lane >> 3); // kv row
      const int sc   = (lane & 7) ^ (row & 7); // global source chunk
      __builtin_amdgcn_global_load_lds(
          (gvoid_t*)(kb + (size_t)row * kE + sc * 8),
          (lvoid_t*)(Kt + slot * 512), 16, 0, 0);
    }
    // ---- stage Vt = K^T, swizzled scalar writes (2-way max) ----
    #pragma unroll
    for (int p = 0; p < 2; ++p) {
      const int sc8 = p * 4 + w;               // s-chunk 0..7
      short8v v = *(const short8v*)(kb + (size_t)lane * kE + 8 * sc8);
      #pragma unroll
      for (int j = 0; j < 8; ++j) {
        const int s = 8 * sc8 + j;
        Vt[s * 64 + (((lane >> 3) ^ (s & 7)) << 3) + (lane & 7)] = v[j];
      }
    }
    __syncthreads();

    // ---- S = Q K^T ----
    f32x4 sacc[2][4];
    #pragma unroll
    for (int m = 0; m < 2; ++m)
      #pragma unroll
      for (int n = 0; n < 4; ++n)
        #pragma unroll
        for (int r = 0; r < 4; ++r) sacc[m][n][r] = 0.f;
    #pragma unroll
    for (int kk = 0; kk < 2; ++kk) {
      bf16x8 bfr[4];
      #pragma unroll
      for (int n = 0; n < 4; ++n)
        bfr[n] = *(const bf16x8*)(Kt + (16 * n + lr) * 64 + (((4 * kk + g) ^ swz) << 3));
      __builtin_amdgcn_s_setprio(1);
      #pragma unroll
      for (int m = 0; m < 2; ++m)
        #pragma unroll
        for (int n = 0; n < 4; ++n)
          sacc[m][n] = __builtin_amdgcn_mfma_f32_16x16x32_bf16(qf[m][kk], bfr[n], sacc[m][n], 0, 0, 0);
      __builtin_amdgcn_s_setprio(0);
    }

    // ---- online softmax, deferred rescale (THR=8) ----
    float tmax[2][4];
    bool small = true;
    #pragma unroll
    for (int m = 0; m < 2; ++m)
      #pragma unroll
      for (int r = 0; r < 4; ++r) {
        float t = fmaxf(fmaxf(sacc[m][0][r], sacc[m][1][r]),
                        fmaxf(sacc[m][2][r], sacc[m][3][r]));
        t = fmaxf(t, __shfl_xor(t, 1));
        t = fmaxf(t, __shfl_xor(t, 2));
        t = fmaxf(t, __shfl_xor(t, 4));
        t = fmaxf(t, __shfl_xor(t, 8));
        tmax[m][r] = t;
        small = small && (t <= mrow[m][r] + 8.f);
      }
    if (!__all(small)) {
      #pragma unroll
      for (int m = 0; m < 2; ++m)
        #pragma unroll
        for (int r = 0; r < 4; ++r) {
          const float mn = fmaxf(mrow[m][r], tmax[m][r]);
          const float a = fexp2((mrow[m][r] - mn) * 1.44269504f);
          mrow[m][r] = mn;
          lacc[m][r] *= a;
          #pragma unroll
          for (int n = 0; n < 4; ++n) oacc[m][n][r] *= a;
        }
    }
    // P = exp2((S - m)*log2e), wave-private store (no barrier needed)
    #pragma unroll
    for (int m = 0; m < 2; ++m)
      #pragma unroll
      for (int n = 0; n < 4; ++n)
        #pragma unroll
        for (int r = 0; r < 4; ++r) {
          const float pv = fexp2((sacc[m][n][r] - mrow[m][r]) * 1.44269504f);
          const int q = w * 32 + m * 16 + 4 * g + r;
          Pt[q * 64 + (((2 * n + (lr >> 3)) ^ ((4 * g + r) & 7)) << 3) + (lr & 7)] = bfc(pv);
        }

    // ---- O += P V ; l += P @ ones ----
    #pragma unroll
    for (int kk = 0; kk < 2; ++kk) {
      bf16x8 pa[2], vfr[4];
      #pragma unroll
      for (int m = 0; m < 2; ++m)
        pa[m] = *(const bf16x8*)(Pt + (w * 32 + m * 16 + lr) * 64 + (((4 * kk + g) ^ swz) << 3));
      #pragma unroll
      for (int n = 0; n < 4; ++n)
        vfr[n] = *(const bf16x8*)(Vt + (16 * n + lr) * 64 + (((4 * kk + g) ^ swz) << 3));
      __builtin_amdgcn_s_setprio(1);
      #pragma unroll
      for (int m = 0; m < 2; ++m) {
        #pragma unroll
        for (int n = 0; n < 4; ++n)
          oacc[m][n] = __builtin_amdgcn_mfma_f32_16x16x32_bf16(pa[m], vfr[n], oacc[m][n], 0, 0, 0);
        lacc[m] = __builtin_amdgcn_mfma_f32_16x16x32_bf16(pa[m], onef, lacc[m], 0, 0, 0);
      }
      __builtin_amdgcn_s_setprio(0);
    }
    __syncthreads();  // Kt/Vt reads done before next staging
  }

  // ---- epilogue: O / l ----
  #pragma unroll
  for (int m = 0; m < 2; ++m)
    #pragma unroll
    for (int r = 0; r < 4; ++r) {
      const float inv = 1.f / lacc[m][r];
      const size_t qoff = base + (size_t)(q0 + w * 32 + m * 16 + 4 * g + r) * kE;
      #pragma unroll
      for (int n = 0; n < 4; ++n)
        AO[qoff + 16 * n + lr] = bfc(oacc[m][n][r] * inv);
    }
}

// ---------------- launch ----------------
extern "C" void kernel_launch(void* const* d_in, const int* in_sizes, int n_in,
                              void* d_out, int out_size, void* d_ws, size_t ws_size,
                              hipStream_t stream) {
  const float* x  = (const float*)d_in[0];
  const float* Wk = (const float*)d_in[1];
  const float* Wq = (const float*)d_in[2];
  const float* Wo = (const float*)d_in[3];
  const float* bo = (const float*)d_in[4];
  float* out = (float*)d_out;

  const size_t nXE = (size_t)kRows * kE;  // 8388608
  const size_t nW  = (size_t)kE * kE;     // 1048576

  short* Xb  = (short*)d_ws;
  short* Kb  = Xb  + nXE;
  short* Qb  = Kb  + nXE;
  short* WkT = Qb  + nXE;
  short* WqT = WkT + nW;
  short* WoT = WqT + nW;
  short* AO  = Xb;  // reuse: x no longer needed after projections

  // x -> bf16
  cvt_bf16<<<dim3(nXE / (4 * 256)), 256, 0, stream>>>(x, Xb);
  // W^T -> bf16
  transpose_cvt<<<dim3(32, 32), 256, 0, stream>>>(Wk, WkT);
  transpose_cvt<<<dim3(32, 32), 256, 0, stream>>>(Wq, WqT);
  transpose_cvt<<<dim3(32, 32), 256, 0, stream>>>(Wo, WoT);

  // K (=V) and Q projections; fold score scale E^-0.5 = 1/32 into Q
  gemm_bt<1><<<dim3(kE / 128, kRows / 128), 256, 0, stream>>>(
      Xb, WkT, (void*)Kb, nullptr, 1.0f, kRows, kE, kE);
  gemm_bt<1><<<dim3(kE / 128, kRows / 128), 256, 0, stream>>>(
      Xb, WqT, (void*)Qb, nullptr, 0.03125f, kRows, kE, kE);

  // attention (writes AO over Xb)
  attn_kernel<<<dim3(kT / 128, kB * kH), 256, 0, stream>>>(Qb, Kb, AO);

  // output projection + bias
  gemm_bt<0><<<dim3(kE / 128, kRows / 128), 256, 0, stream>>>(
      AO, WoT, (void*)out, bo, 1.0f, kRows, kE, kE);
}

// Round 3
// 243.497 us; speedup vs baseline: 1.5776x; 1.3020x over previous
//
#include <hip/hip_runtime.h>
#include <hip/hip_bf16.h>
#include <stdint.h>

// Problem constants
static constexpr int kB = 4;
static constexpr int kT = 2048;
static constexpr int kE = 1024;
static constexpr int kH = 16;
static constexpr int kS = 64;          // head dim
static constexpr int kRows = kB * kT;  // 8192

typedef __attribute__((ext_vector_type(4))) float    f32x4;
typedef __attribute__((ext_vector_type(4))) float    float4v;
typedef __attribute__((ext_vector_type(8))) __bf16   bf16x8;
typedef __attribute__((ext_vector_type(8))) short    short8v;
typedef __attribute__((ext_vector_type(4))) short    short4v;
typedef __attribute__((ext_vector_type(2))) unsigned u32x2;

typedef const __attribute__((address_space(1))) void gvoid_t;
typedef __attribute__((address_space(3))) void lvoid_t;

__device__ __forceinline__ short f2bf(float f) {
  union { float f; unsigned u; } c; c.f = f;
  unsigned r = (c.u + 0x7FFFu + ((c.u >> 16) & 1u)) >> 16;
  return (short)(r & 0xFFFFu);
}

__device__ __forceinline__ short bfc(float f) {
  union { __bf16 b; short s; } u; u.b = (__bf16)f; return u.s;
}

// v_cvt_pk_bf16_f32: D[15:0]=bf16(lo), D[31:16]=bf16(hi). No builtin on gfx950.
__device__ __forceinline__ unsigned cvt_pk(float lo, float hi) {
  unsigned r;
  asm("v_cvt_pk_bf16_f32 %0, %1, %2" : "=v"(r) : "v"(lo), "v"(hi));
  return r;
}

__device__ __forceinline__ float fexp2(float x) { return exp2f(x); }

// ---------------- convert f32 -> bf16 (vectorized) ----------------
__global__ void cvt_bf16(const float* __restrict__ in, short* __restrict__ out) {
  size_t i = (size_t)(blockIdx.x * blockDim.x + threadIdx.x) * 4;
  float4v x = *(const float4v*)(in + i);
  short4v o;
  o[0] = f2bf(x[0]); o[1] = f2bf(x[1]); o[2] = f2bf(x[2]); o[3] = f2bf(x[3]);
  *(short4v*)(out + i) = o;
}

// ---------------- transpose + convert: W[k][n] f32 -> WT[n][k] bf16 ----------------
__global__ void transpose_cvt(const float* __restrict__ W, short* __restrict__ WT) {
  __shared__ float tile[32][33];
  const int tx = threadIdx.x & 31, ty = threadIdx.x >> 5;  // 32 x 8
  const int c = blockIdx.x * 32, r = blockIdx.y * 32;
  #pragma unroll
  for (int i = ty; i < 32; i += 8)
    tile[i][tx] = W[(size_t)(r + i) * kE + c + tx];
  __syncthreads();
  #pragma unroll
  for (int i = ty; i < 32; i += 8)
    WT[(size_t)(c + i) * kE + r + tx] = f2bf(tile[tx][i]);
}

// ---------------- bf16 GEMM (m97 recipe): C = scale*(A @ BT^T) (+bias) ----------------
// 128x128 tile, BK=64, linear [128][64] LDS via global_load_lds(16B) with
// source-chunk XOR swizzle (chunk ^= row&7); grid 512 blocks, XCD-swizzled.
template<int OUT_BF16>
__global__ __launch_bounds__(256)
void gemm_bt(const short* __restrict__ A, const short* __restrict__ BT,
             void* __restrict__ Cout, const float* __restrict__ bias,
             float scale, int M, int N, int K) {
  __shared__ short As[128 * 64];
  __shared__ short Bs[128 * 64];
  const int tid = threadIdx.x;
  const int w = tid >> 6, lane = tid & 63;
  const int g = lane >> 4, lr = lane & 15;
  const int bid = blockIdx.x;
  const int id = (bid & 7) * 64 + (bid >> 3);   // XCD swizzle (512 % 8 == 0)
  const int n0 = (id & 7) * 128, m0 = (id >> 3) * 128;
  const int wr = w >> 1, wc = w & 1;
  const int srow = lane >> 3, sch = lane & 7;
  const int swz = lr & 7;

  f32x4 acc[4][4];
  #pragma unroll
  for (int m = 0; m < 4; ++m)
    #pragma unroll
    for (int n = 0; n < 4; ++n)
      #pragma unroll
      for (int r = 0; r < 4; ++r) acc[m][n][r] = 0.f;

  for (int kt = 0; kt < K; kt += 64) {
    #pragma unroll
    for (int i = 0; i < 4; ++i) {
      const int slot = w * 4 + i;
      const int row = slot * 8 + srow;
      const int sc = sch ^ srow;   // source chunk pre-swizzle
      __builtin_amdgcn_global_load_lds(
          (gvoid_t*)(A + (size_t)(m0 + row) * K + kt + 8 * sc),
          (lvoid_t*)(As + slot * 512), 16, 0, 0);
      __builtin_amdgcn_global_load_lds(
          (gvoid_t*)(BT + (size_t)(n0 + row) * K + kt + 8 * sc),
          (lvoid_t*)(Bs + slot * 512), 16, 0, 0);
    }
    __syncthreads();
    #pragma unroll
    for (int kk = 0; kk < 2; ++kk) {
      bf16x8 af[4], bfr[4];
      #pragma unroll
      for (int m = 0; m < 4; ++m)
        af[m] = *(const bf16x8*)(As + (wr * 64 + m * 16 + lr) * 64 + (((4 * kk + g) ^ swz) << 3));
      #pragma unroll
      for (int n = 0; n < 4; ++n)
        bfr[n] = *(const bf16x8*)(Bs + (wc * 64 + n * 16 + lr) * 64 + (((4 * kk + g) ^ swz) << 3));
      __builtin_amdgcn_s_setprio(1);
      #pragma unroll
      for (int m = 0; m < 4; ++m)
        #pragma unroll
        for (int n = 0; n < 4; ++n)
          acc[m][n] = __builtin_amdgcn_mfma_f32_16x16x32_bf16(af[m], bfr[n], acc[m][n], 0, 0, 0);
      __builtin_amdgcn_s_setprio(0);
    }
    __syncthreads();
  }

  const int crow = m0 + wr * 64, ccol = n0 + wc * 64;
  if (OUT_BF16) {
    short* C = (short*)Cout;
    #pragma unroll
    for (int m = 0; m < 4; ++m)
      #pragma unroll
      for (int n = 0; n < 4; ++n)
        #pragma unroll
        for (int r = 0; r < 4; ++r)
          C[(size_t)(crow + m * 16 + 4 * g + r) * N + ccol + n * 16 + lr] =
              bfc(acc[m][n][r] * scale);
  } else {
    float* C = (float*)Cout;
    float bv[4];
    #pragma unroll
    for (int n = 0; n < 4; ++n) bv[n] = bias ? bias[ccol + n * 16 + lr] : 0.f;
    #pragma unroll
    for (int m = 0; m < 4; ++m)
      #pragma unroll
      for (int n = 0; n < 4; ++n)
        #pragma unroll
        for (int r = 0; r < 4; ++r)
          C[(size_t)(crow + m * 16 + 4 * g + r) * N + ccol + n * 16 + lr] =
              acc[m][n][r] * scale + bv[n];
  }
}

// ---------------- flash attention; V == K (faithful to reference bug) ----------------
// Swapped layout: S^T = mfma(K, Q); O^T = mfma(V^T, P).  Q pre-scaled by
// E^-0.5 * log2(e) so softmax is pure exp2.  QBLK=128 (4 waves x 32 q),
// KVBLK=64.  Kt double-buffered via global_load_lds (pre-swizzled source);
// Vt single-buffer (reg-staged transpose); Pt wave-private.
// All LDS rows are 128B; 16B chunk c at row r lives at physical c^(r&7).

__device__ __forceinline__ void attn_tile(
    bool pf, const short* __restrict__ kbn, short* KtN, const short* KtC,
    short* Vt, short* PtW,
    short8v& vc0, short8v& vc1, short8v& vn0, short8v& vn1,
    const bf16x8 (&qfr)[2][2], bf16x8 onef,
    f32x4 (&oacc)[4][2], f32x4 (&lacc)[2], float (&mrow)[2],
    const int w, const int lane, const int g, const int lr) {
  const int swz = lr & 7;

  // ---- prefetch next tile (loads stay in flight across the barrier) ----
  if (pf) {
    vn0 = *(const short8v*)(kbn + (size_t)lane * kE + 8 * w);
    vn1 = *(const short8v*)(kbn + (size_t)lane * kE + 8 * (4 + w));
    #pragma unroll
    for (int i = 0; i < 2; ++i) {
      const int slot = w * 2 + i, row = slot * 8 + (lane >> 3);
      const int sc = (lane & 7) ^ (row & 7);
      __builtin_amdgcn_global_load_lds(
          (gvoid_t*)(kbn + (size_t)row * kE + 8 * sc),
          (lvoid_t*)(KtN + slot * 512), 16, 0, 0);
    }
    asm volatile("s_waitcnt vmcnt(4)" ::: "memory");  // current tile's 4 loads done
  } else {
    asm volatile("s_waitcnt vmcnt(0)" ::: "memory");
  }

  // ---- Vt <- K^T (current tile) from staged regs, swizzled ----
  #pragma unroll
  for (int p = 0; p < 2; ++p) {
    const short8v v = p ? vc1 : vc0;
    const int s0 = 8 * (4 * p + w);
    #pragma unroll
    for (int j = 0; j < 8; ++j)
      Vt[(s0 + j) * 64 + (((lane >> 3) ^ j) << 3) + (lane & 7)] = v[j];
  }
  asm volatile("s_waitcnt lgkmcnt(0)" ::: "memory");
  asm volatile("s_barrier" ::: "memory");   // Kt[cur] + Vt visible

  // ---- S^T = K Q^T ----
  f32x4 sacc[4][2];
  #pragma unroll
  for (int kvf = 0; kvf < 4; ++kvf)
    #pragma unroll
    for (int qf = 0; qf < 2; ++qf)
      #pragma unroll
      for (int r = 0; r < 4; ++r) sacc[kvf][qf][r] = 0.f;
  #pragma unroll
  for (int kk = 0; kk < 2; ++kk) {
    bf16x8 kf[4];
    #pragma unroll
    for (int kvf = 0; kvf < 4; ++kvf)
      kf[kvf] = *(const bf16x8*)(KtC + (16 * kvf + lr) * 64 + (((4 * kk + g) ^ swz) << 3));
    __builtin_amdgcn_s_setprio(1);
    #pragma unroll
    for (int kvf = 0; kvf < 4; ++kvf)
      #pragma unroll
      for (int qf = 0; qf < 2; ++qf)
        sacc[kvf][qf] = __builtin_amdgcn_mfma_f32_16x16x32_bf16(kf[kvf], qfr[qf][kk], sacc[kvf][qf], 0, 0, 0);
    __builtin_amdgcn_s_setprio(0);
  }

  // ---- online softmax (q-row = lane&15; only shfl 16/32 cross g-lanes) ----
  float nmax[2];
  #pragma unroll
  for (int qf = 0; qf < 2; ++qf) {
    float t = sacc[0][qf][0];
    #pragma unroll
    for (int kvf = 0; kvf < 4; ++kvf)
      #pragma unroll
      for (int r = 0; r < 4; ++r)
        if (kvf | r) t = fmaxf(t, sacc[kvf][qf][r]);
    t = fmaxf(t, __shfl_xor(t, 16));
    t = fmaxf(t, __shfl_xor(t, 32));
    nmax[qf] = t;
  }
  const bool small = (nmax[0] <= mrow[0] + 8.f) & (nmax[1] <= mrow[1] + 8.f);
  if (!__all(small)) {
    #pragma unroll
    for (int qf = 0; qf < 2; ++qf) {
      const float mn = fmaxf(mrow[qf], nmax[qf]);
      const float a = fexp2(mrow[qf] - mn);
      mrow[qf] = mn;
      #pragma unroll
      for (int r = 0; r < 4; ++r) lacc[qf][r] *= a;
      #pragma unroll
      for (int sf = 0; sf < 4; ++sf)
        #pragma unroll
        for (int r = 0; r < 4; ++r) oacc[sf][qf][r] *= a;
    }
  }

  // ---- P = exp2(S^T - m); pack 4 bf16 -> one ds_write_b64 per (qf,kvf) ----
  #pragma unroll
  for (int qf = 0; qf < 2; ++qf)
    #pragma unroll
    for (int kvf = 0; kvf < 4; ++kvf) {
      const float p0 = fexp2(sacc[kvf][qf][0] - mrow[qf]);
      const float p1 = fexp2(sacc[kvf][qf][1] - mrow[qf]);
      const float p2 = fexp2(sacc[kvf][qf][2] - mrow[qf]);
      const float p3 = fexp2(sacc[kvf][qf][3] - mrow[qf]);
      u32x2 pw;
      pw[0] = cvt_pk(p0, p1);
      pw[1] = cvt_pk(p2, p3);
      *(u32x2*)(PtW + (qf * 16 + lr) * 64 +
                (((2 * kvf + (g >> 1)) ^ swz) << 3) + ((g & 1) << 2)) = pw;
    }

  // ---- O^T += V^T P^T ; l += rowsum(P) via ones-MFMA ----
  #pragma unroll
  for (int kk = 0; kk < 2; ++kk) {
    bf16x8 pb[2], vf[4];
    #pragma unroll
    for (int qf = 0; qf < 2; ++qf)
      pb[qf] = *(const bf16x8*)(PtW + (qf * 16 + lr) * 64 + (((4 * kk + g) ^ swz) << 3));
    #pragma unroll
    for (int sf = 0; sf < 4; ++sf)
      vf[sf] = *(const bf16x8*)(Vt + (16 * sf + lr) * 64 + (((4 * kk + g) ^ swz) << 3));
    __builtin_amdgcn_s_setprio(1);
    #pragma unroll
    for (int sf = 0; sf < 4; ++sf)
      #pragma unroll
      for (int qf = 0; qf < 2; ++qf)
        oacc[sf][qf] = __builtin_amdgcn_mfma_f32_16x16x32_bf16(vf[sf], pb[qf], oacc[sf][qf], 0, 0, 0);
    #pragma unroll
    for (int qf = 0; qf < 2; ++qf)
      lacc[qf] = __builtin_amdgcn_mfma_f32_16x16x32_bf16(onef, pb[qf], lacc[qf], 0, 0, 0);
    __builtin_amdgcn_s_setprio(0);
  }
  asm volatile("s_barrier" ::: "memory");   // all reads done before next overwrite
}

__global__ __launch_bounds__(256)
void attn_kernel(const short* __restrict__ Qb, const short* __restrict__ Kb,
                 short* __restrict__ AO) {
  __shared__ short Kt[2][64 * 64];   // 16 KB (double-buffered)
  __shared__ short Vt[64 * 64];      // 8 KB
  __shared__ short Pt[4][32 * 64];   // 16 KB (wave-private)

  const int tid = threadIdx.x;
  const int w = tid >> 6, lane = tid & 63;
  const int g = lane >> 4, lr = lane & 15;
  const int bid = blockIdx.x;
  const int id = (bid & 7) * 128 + (bid >> 3);  // XCD swizzle (1024 % 8 == 0)
  const int q0 = (id & 15) * 128;
  const int bh = id >> 4;
  const size_t base = (size_t)(bh >> 4) * kT * kE + (size_t)(bh & 15) * kS;

  const short* Kbh = Kb + base;
  short* PtW = &Pt[w][0];

  // Q fragments (pre-scaled by E^-0.5 * log2e in the projection GEMM)
  bf16x8 qfr[2][2];
  #pragma unroll
  for (int qf = 0; qf < 2; ++qf)
    #pragma unroll
    for (int kk = 0; kk < 2; ++kk)
      qfr[qf][kk] = *(const bf16x8*)(Qb + base +
          (size_t)(q0 + w * 32 + qf * 16 + lr) * kE + 32 * kk + 8 * g);

  f32x4 oacc[4][2];
  f32x4 lacc[2];
  float mrow[2];
  #pragma unroll
  for (int sf = 0; sf < 4; ++sf)
    #pragma unroll
    for (int qf = 0; qf < 2; ++qf)
      #pragma unroll
      for (int r = 0; r < 4; ++r) oacc[sf][qf][r] = 0.f;
  #pragma unroll
  for (int qf = 0; qf < 2; ++qf) {
    #pragma unroll
    for (int r = 0; r < 4; ++r) lacc[qf][r] = 0.f;
    mrow[qf] = -1e30f;
  }

  short8v ones_i;
  #pragma unroll
  for (int j = 0; j < 8; ++j) ones_i[j] = 0x3F80;
  const bf16x8 onef = *(const bf16x8*)&ones_i;

  // ---- prologue: issue tile 0 ----
  short8v v0a, v0b, v1a, v1b;
  v0a = *(const short8v*)(Kbh + (size_t)lane * kE + 8 * w);
  v0b = *(const short8v*)(Kbh + (size_t)lane * kE + 8 * (4 + w));
  #pragma unroll
  for (int i = 0; i < 2; ++i) {
    const int slot = w * 2 + i, row = slot * 8 + (lane >> 3);
    const int sc = (lane & 7) ^ (row & 7);
    __builtin_amdgcn_global_load_lds(
        (gvoid_t*)(Kbh + (size_t)row * kE + 8 * sc),
        (lvoid_t*)(&Kt[0][0] + slot * 512), 16, 0, 0);
  }

  for (int tp = 0; tp < 16; ++tp) {
    attn_tile(true, Kbh + (size_t)(2 * tp + 1) * 64 * kE, &Kt[1][0], &Kt[0][0],
              Vt, PtW, v0a, v0b, v1a, v1b, qfr, onef, oacc, lacc, mrow,
              w, lane, g, lr);
    attn_tile(tp < 15, Kbh + (size_t)(2 * tp + 2) * 64 * kE, &Kt[0][0], &Kt[1][0],
              Vt, PtW, v1a, v1b, v0a, v0b, qfr, onef, oacc, lacc, mrow,
              w, lane, g, lr);
  }

  // ---- epilogue: O = O^T / l, b64 stores ----
  #pragma unroll
  for (int qf = 0; qf < 2; ++qf) {
    const float inv = 1.f / lacc[qf][0];
    short* aop = AO + base + (size_t)(q0 + w * 32 + qf * 16 + lr) * kE;
    #pragma unroll
    for (int sf = 0; sf < 4; ++sf) {
      u32x2 ov;
      ov[0] = cvt_pk(oacc[sf][qf][0] * inv, oacc[sf][qf][1] * inv);
      ov[1] = cvt_pk(oacc[sf][qf][2] * inv, oacc[sf][qf][3] * inv);
      *(u32x2*)(aop + 16 * sf + 4 * g) = ov;
    }
  }
}

// ---------------- launch ----------------
extern "C" void kernel_launch(void* const* d_in, const int* in_sizes, int n_in,
                              void* d_out, int out_size, void* d_ws, size_t ws_size,
                              hipStream_t stream) {
  const float* x  = (const float*)d_in[0];
  const float* Wk = (const float*)d_in[1];
  const float* Wq = (const float*)d_in[2];
  const float* Wo = (const float*)d_in[3];
  const float* bo = (const float*)d_in[4];
  float* out = (float*)d_out;

  const size_t nXE = (size_t)kRows * kE;  // 8388608
  const size_t nW  = (size_t)kE * kE;     // 1048576

  short* Xb  = (short*)d_ws;
  short* Kb  = Xb  + nXE;
  short* Qb  = Kb  + nXE;
  short* WkT = Qb  + nXE;
  short* WqT = WkT + nW;
  short* WoT = WqT + nW;
  short* AO  = Xb;  // reuse: x no longer needed after projections

  cvt_bf16<<<dim3(nXE / (4 * 256)), 256, 0, stream>>>(x, Xb);
  transpose_cvt<<<dim3(32, 32), 256, 0, stream>>>(Wk, WkT);
  transpose_cvt<<<dim3(32, 32), 256, 0, stream>>>(Wq, WqT);
  transpose_cvt<<<dim3(32, 32), 256, 0, stream>>>(Wo, WoT);

  // K (=V) and Q projections; fold E^-0.5 * log2(e) into Q so softmax is exp2
  gemm_bt<1><<<dim3(512), 256, 0, stream>>>(
      Xb, WkT, (void*)Kb, nullptr, 1.0f, kRows, kE, kE);
  gemm_bt<1><<<dim3(512), 256, 0, stream>>>(
      Xb, WqT, (void*)Qb, nullptr, 0.03125f * 1.44269504f, kRows, kE, kE);

  attn_kernel<<<dim3(1024), 256, 0, stream>>>(Qb, Kb, AO);

  gemm_bt<0><<<dim3(512), 256, 0, stream>>>(
      AO, WoT, (void*)out, bo, 1.0f, kRows, kE, kE);
}